// Round 1
// baseline (717.559 us; speedup 1.0000x reference)
//
#include <hip/hip_runtime.h>

// MultiHeadBiaffine: x(4,256,1024) fp32; Wh,Wv(512,1024); bh,bv(512); W(4,128,128,128)
// out (4,256,256,512) fp32.
// Decomposition:
//   h[b,l,h,x] = leaky(x @ Wh^T), v likewise        (k1, MFMA bf16)
//   u[b,h,l,d,y] = sum_x h * W[h,d,x,y]             (k2, MFMA bf16, per-b chunk)
//   out[b,l,k,h*128+d] = sum_y v[b,k,h,y]*u[...]    (k3, MFMA bf16, fp32 out)
// Workspace: Wb(16MiB) | hmat(1MiB) | vmat(1MiB) | u-chunk(32MiB) = 50MiB.

typedef unsigned short u16;
typedef __attribute__((ext_vector_type(8))) short short8;
typedef __attribute__((ext_vector_type(4))) float f32x4;

__device__ __forceinline__ u16 f2bf(float f) {
  union { float f; unsigned u; } c; c.f = f;
  unsigned u = c.u;
  return (u16)((u + 0x7FFFu + ((u >> 16) & 1u)) >> 16);  // RNE
}

__device__ __forceinline__ unsigned pack2(float a, float b) {
  return ((unsigned)f2bf(b) << 16) | (unsigned)f2bf(a);
}

__device__ __forceinline__ uint4 pack8(const float* __restrict__ g) {
  float4 f0 = *(const float4*)(g);
  float4 f1 = *(const float4*)(g + 4);
  uint4 o;
  o.x = pack2(f0.x, f0.y);
  o.y = pack2(f0.z, f0.w);
  o.z = pack2(f1.x, f1.y);
  o.w = pack2(f1.z, f1.w);
  return o;
}

// ---- shared 128x128-tile MFMA core (gemm_bt: C[m][n] = sum_k A[m][k]*Bt[n][k]) ----
// LDS tiles As/Bs are [128 rows][32 k] bf16. Fragment layout (verified m89/m91):
//  A frag: lane holds A[m=lane&15][k=(lane>>4)*8 + j]; B frag mirrors with n=lane&15.
//  C/D:    col = lane&15, row = (lane>>4)*4 + reg.
__device__ __forceinline__ void tile_compute(const u16* As, const u16* Bs,
                                             f32x4 acc[4][4], int wm, int wn,
                                             int frow, int kq) {
  short8 af[4], bfr[4];
#pragma unroll
  for (int i = 0; i < 4; ++i)
    af[i] = *(const short8*)(As + (size_t)(wm + i * 16 + frow) * 32 + kq);
#pragma unroll
  for (int j = 0; j < 4; ++j)
    bfr[j] = *(const short8*)(Bs + (size_t)(wn + j * 16 + frow) * 32 + kq);
#pragma unroll
  for (int i = 0; i < 4; ++i)
#pragma unroll
    for (int j = 0; j < 4; ++j)
      acc[i][j] = __builtin_amdgcn_mfma_f32_16x16x32_bf16(af[i], bfr[j], acc[i][j], 0, 0, 0);
}

__device__ __forceinline__ void stage_bf16(const u16* __restrict__ ga,
                                           const u16* __restrict__ gb,
                                           u16* As, u16* Bs, int r, int seg) {
  uint4 a0 = *(const uint4*)ga;
  uint4 a1 = *(const uint4*)(ga + 8);
  uint4 b0 = *(const uint4*)gb;
  uint4 b1 = *(const uint4*)(gb + 8);
  __syncthreads();  // previous iter's LDS reads complete
  *(uint4*)(As + r * 32 + seg * 16) = a0;
  *(uint4*)(As + r * 32 + seg * 16 + 8) = a1;
  *(uint4*)(Bs + r * 32 + seg * 16) = b0;
  *(uint4*)(Bs + r * 32 + seg * 16 + 8) = b1;
  __syncthreads();
}

// ---- k0: W[h][d][x][y] fp32 -> Wb[h][d][y][x] bf16 (transpose last two dims) ----
__global__ __launch_bounds__(256) void k0_twp(const float* __restrict__ W,
                                              u16* __restrict__ Wb) {
  __shared__ u16 t[128][129];
  int slice = blockIdx.x;  // h*128+d
  const float* src = W + (size_t)slice * 16384;
  u16* dst = Wb + (size_t)slice * 16384;
  int tid = threadIdx.x;
  for (int e = tid; e < 16384; e += 256) {
    int xi = e >> 7, yi = e & 127;
    t[xi][yi] = f2bf(src[e]);
  }
  __syncthreads();
  for (int e = tid; e < 16384; e += 256) {
    int yi = e >> 7, xi = e & 127;
    dst[e] = t[xi][yi];
  }
}

// ---- k1: fused head/tail MLP. M=1024 rows (b,l), N=1024 ([Wh|Wv]), K=1024 ----
__global__ __launch_bounds__(256) void k1_mlp(const float* __restrict__ x,
                                              const float* __restrict__ Wh,
                                              const float* __restrict__ bh,
                                              const float* __restrict__ Wv,
                                              const float* __restrict__ bv,
                                              u16* __restrict__ hmat,
                                              u16* __restrict__ vmat) {
  __shared__ __align__(16) u16 As[128 * 32];
  __shared__ __align__(16) u16 Bs[128 * 32];
  int tid = threadIdx.x;
  int m0 = blockIdx.y * 128;
  int n0 = blockIdx.x * 128;
  bool isV = (n0 >= 512);
  const float* Wsel = isV ? Wv : Wh;
  const float* bsel = isV ? bv : bh;
  int nW = isV ? (n0 - 512) : n0;
  int wave = tid >> 6, lane = tid & 63;
  int wm = (wave & 1) * 64, wn = (wave >> 1) * 64;
  int r = tid >> 1, seg = tid & 1;
  int frow = lane & 15, kq = (lane >> 4) * 8;
  f32x4 acc[4][4];
  f32x4 z = {0.f, 0.f, 0.f, 0.f};
#pragma unroll
  for (int i = 0; i < 4; ++i)
#pragma unroll
    for (int j = 0; j < 4; ++j) acc[i][j] = z;

  for (int k0 = 0; k0 < 1024; k0 += 32) {
    const float* ga = x + (size_t)(m0 + r) * 1024 + k0 + seg * 16;
    const float* gb = Wsel + (size_t)(nW + r) * 1024 + k0 + seg * 16;
    uint4 a0 = pack8(ga), a1 = pack8(ga + 8);
    uint4 b0 = pack8(gb), b1 = pack8(gb + 8);
    __syncthreads();
    *(uint4*)(As + r * 32 + seg * 16) = a0;
    *(uint4*)(As + r * 32 + seg * 16 + 8) = a1;
    *(uint4*)(Bs + r * 32 + seg * 16) = b0;
    *(uint4*)(Bs + r * 32 + seg * 16 + 8) = b1;
    __syncthreads();
    tile_compute(As, Bs, acc, wm, wn, frow, kq);
  }

  u16* dst = isV ? vmat : hmat;
#pragma unroll
  for (int i = 0; i < 4; ++i)
#pragma unroll
    for (int j = 0; j < 4; ++j)
#pragma unroll
      for (int rg = 0; rg < 4; ++rg) {
        int ml = wm + i * 16 + (lane >> 4) * 4 + rg;
        int nl = wn + j * 16 + (lane & 15);
        int mg = m0 + ml;  // b*256+l
        int ng = n0 + nl;  // feature
        float val = acc[i][j][rg] + bsel[nW + nl];
        val = (val >= 0.f) ? val : 0.01f * val;
        int bb = mg >> 8, ll = mg & 255;
        int head = (ng & 511) >> 7, xcol = ng & 127;
        dst[(((size_t)(bb * 4 + head)) * 256 + ll) * 128 + xcol] = f2bf(val);
      }
}

// ---- k2: u[h][l][dy] = hmat[b][h] (256x128) @ Wb[h] (16384x128)^T, per-b chunk ----
__global__ __launch_bounds__(256) void k2_uw(const u16* __restrict__ hmat,
                                             const u16* __restrict__ Wb,
                                             u16* __restrict__ u, int b) {
  __shared__ __align__(16) u16 As[128 * 32];
  __shared__ __align__(16) u16 Bs[128 * 32];
  int tid = threadIdx.x;
  int h = blockIdx.z;
  int m0 = blockIdx.y * 128;  // l tile
  int n0 = blockIdx.x * 128;  // dy tile
  const u16* A = hmat + ((size_t)(b * 4 + h) * 256 + m0) * 128;
  const u16* Bt = Wb + ((size_t)h * 16384 + n0) * 128;
  int wave = tid >> 6, lane = tid & 63;
  int wm = (wave & 1) * 64, wn = (wave >> 1) * 64;
  int r = tid >> 1, seg = tid & 1;
  int frow = lane & 15, kq = (lane >> 4) * 8;
  f32x4 acc[4][4];
  f32x4 z = {0.f, 0.f, 0.f, 0.f};
#pragma unroll
  for (int i = 0; i < 4; ++i)
#pragma unroll
    for (int j = 0; j < 4; ++j) acc[i][j] = z;

  for (int k0 = 0; k0 < 128; k0 += 32) {
    stage_bf16(A + (size_t)r * 128 + k0 + seg * 16,
               Bt + (size_t)r * 128 + k0 + seg * 16, As, Bs, r, seg);
    tile_compute(As, Bs, acc, wm, wn, frow, kq);
  }

  u16* C = u + ((size_t)h * 256 + m0) * 16384 + n0;
#pragma unroll
  for (int i = 0; i < 4; ++i)
#pragma unroll
    for (int j = 0; j < 4; ++j)
#pragma unroll
      for (int rg = 0; rg < 4; ++rg) {
        int ml = wm + i * 16 + (lane >> 4) * 4 + rg;
        int nl = wn + j * 16 + (lane & 15);
        C[(size_t)ml * 16384 + nl] = f2bf(acc[i][j][rg]);
      }
}

// ---- k3: out[b][l][k][h*128+d] = vmat[b][h] (256x128) @ u[h][l] (128d x 128y)^T ----
__global__ __launch_bounds__(256) void k3_out(const u16* __restrict__ vmat,
                                              const u16* __restrict__ u,
                                              float* __restrict__ out, int b) {
  __shared__ __align__(16) u16 As[128 * 32];
  __shared__ __align__(16) u16 Bs[128 * 32];
  int tid = threadIdx.x;
  int h = blockIdx.z;
  int l = blockIdx.y;
  int k0t = blockIdx.x * 128;  // k tile
  const u16* A = vmat + ((size_t)(b * 4 + h) * 256 + k0t) * 128;  // [k][y]
  const u16* Bt = u + ((size_t)h * 256 + l) * 16384;              // [d][y]
  int wave = tid >> 6, lane = tid & 63;
  int wm = (wave & 1) * 64, wn = (wave >> 1) * 64;
  int r = tid >> 1, seg = tid & 1;
  int frow = lane & 15, kq = (lane >> 4) * 8;
  f32x4 acc[4][4];
  f32x4 z = {0.f, 0.f, 0.f, 0.f};
#pragma unroll
  for (int i = 0; i < 4; ++i)
#pragma unroll
    for (int j = 0; j < 4; ++j) acc[i][j] = z;

  for (int k0 = 0; k0 < 128; k0 += 32) {
    stage_bf16(A + (size_t)r * 128 + k0 + seg * 16,
               Bt + (size_t)r * 128 + k0 + seg * 16, As, Bs, r, seg);
    tile_compute(As, Bs, acc, wm, wn, frow, kq);
  }

#pragma unroll
  for (int i = 0; i < 4; ++i)
#pragma unroll
    for (int j = 0; j < 4; ++j)
#pragma unroll
      for (int rg = 0; rg < 4; ++rg) {
        int kk = k0t + wm + i * 16 + (lane >> 4) * 4 + rg;
        int d = wn + j * 16 + (lane & 15);
        out[(((size_t)b * 256 + l) * 256 + kk) * 512 + h * 128 + d] = acc[i][j][rg];
      }
}

extern "C" void kernel_launch(void* const* d_in, const int* in_sizes, int n_in,
                              void* d_out, int out_size, void* d_ws, size_t ws_size,
                              hipStream_t stream) {
  const float* x = (const float*)d_in[0];
  const float* Wh = (const float*)d_in[1];
  const float* bh = (const float*)d_in[2];
  const float* Wv = (const float*)d_in[3];
  const float* bv = (const float*)d_in[4];
  const float* W = (const float*)d_in[5];
  float* out = (float*)d_out;

  char* ws = (char*)d_ws;
  u16* Wb = (u16*)(ws);                          // 16 MiB: [4][128][128y][128x]
  u16* hmat = (u16*)(ws + (16u << 20));          // 1 MiB:  [4][4][256][128]
  u16* vmat = (u16*)(ws + (17u << 20));          // 1 MiB
  u16* u = (u16*)(ws + (18u << 20));             // 32 MiB: per-b [4][256][16384]

  hipLaunchKernelGGL(k0_twp, dim3(512), dim3(256), 0, stream, W, Wb);
  hipLaunchKernelGGL(k1_mlp, dim3(8, 8), dim3(256), 0, stream, x, Wh, bh, Wv, bv,
                     hmat, vmat);
  for (int b = 0; b < 4; ++b) {
    hipLaunchKernelGGL(k2_uw, dim3(128, 2, 4), dim3(256), 0, stream, hmat, Wb, u, b);
    hipLaunchKernelGGL(k3_out, dim3(2, 256, 4), dim3(256), 0, stream, vmat, u, out, b);
  }
}